// Round 13
// baseline (212.911 us; speedup 1.0000x reference)
//
#include <hip/hip_runtime.h>

// CANet fused kernel, round 18.
// Post-mortem r17: tap prefetch WIN (128.3->116.0us, prediction 108-120 hit;
// VGPR stayed 84, no spill). Latency-hiding model validated twice.
// Remaining: ~38K cyc/block vs ~10K phase work -> barrier-serialized
// (16 barriers/block). r18: ping-pong buffer roles to cut barriers + overlap:
//   im2col_t & h2_t live in buf[t&1]; h1_t lives in buf[(t+1)&1].
//   Per iter: G1(read cur->write alt) | Bb | G2(read alt->write cur) | Bc |
//   G3(read cur) PARALLEL staging_{t+1}(write alt) | Ba | swap.
//   B4 gone (absorbed into Ba); staging overlaps G3. Barriers 16 -> 11.
//   Hand-off verified t=0,1: every write lands in a buffer whose readers
//   passed the preceding barrier.
// Tap prefetch for t+1 issued at iter-t start (cover G1+G2 ~5K cyc >> 900).
// Canaries: WRITE 49152KB / FETCH ~74MB / VGPR<=~96 (spill); conflicts flat.
// If dur flat: barriers not the lever -> 2-row blocks next.

#define ACT_S 136     // 272 B rows (16B-aligned) for buf0/buf1 [px][ch]
#define NOISE_BASE 9437184   // 16*9*65536

// d_ws shorts: Wf[128][128]@0, w2[128][128]@16384, w3[16][128]@32768 (2048)
// floats @ WSF_OFF: b1'[128]@0, b2[128]@128, emb[48]@256
#define WSF_OFF 17408
#define WSF_B1 0
#define WSF_B2 128
#define WSF_EMB 256

typedef short bf16x8 __attribute__((ext_vector_type(8)));
typedef float f32x4 __attribute__((ext_vector_type(4)));

__device__ __forceinline__ short f2bf(float f) {
    union { float f; unsigned u; } cv; cv.f = f;
    unsigned r = cv.u + 0x7FFFu + ((cv.u >> 16) & 1u);
    return (short)(r >> 16);
}
// pack two fp32 -> dword of two bf16 (round-half-up): lo16=bf(f0), hi16=bf(f1)
__device__ __forceinline__ unsigned pk2bf(float f0, float f1) {
    union { float f; unsigned u; } a, b; a.f = f0; b.f = f1;
    return __builtin_amdgcn_perm(b.u + 0x8000u, a.u + 0x8000u, 0x07060302u);
}

// fragment-row -> actual channel permutation (within each 32-ch wave block):
// f = base(32) + 16*j + i  ->  o = base + 8*(i>>2) + 4*j + (i&3)
__device__ __forceinline__ int permch(int f) {
    return (f & ~31) + 8 * ((f & 15) >> 2) + 4 * ((f >> 4) & 1) + (f & 3);
}

// ---------------- weight prep (fused Wf/b1') + time embedding ----------------
__global__ void prep_emb_kernel(const float* __restrict__ wpg, const float* __restrict__ bpg,
                                const float* __restrict__ w1g, const float* __restrict__ b1g,
                                const float* __restrict__ w2g, const float* __restrict__ b2g,
                                const float* __restrict__ w3g,
                                const int* __restrict__ t,
                                const float* __restrict__ wt, const float* __restrict__ bt,
                                short* __restrict__ wsb, float* __restrict__ wsf)
{
    const int bid = blockIdx.x, tid = threadIdx.x;
    if (bid < 64) {                       // Wf fragment rows (PERMUTED out-ch)
        int i = bid * 256 + tid;
        int f = i >> 7, kk = i & 127;
        int o = permch(f);
        int qq = kk >> 5, r = kk & 31;
        float v = 0.f;
        if (r < 30 && (r % 10) < 9) {
            int c3 = r / 10, k = r % 10;
            int ic = 3 * qq + c3;
            #pragma unroll
            for (int j = 0; j < 4; ++j)
                v += w1g[o * 48 + 4 * ic + j] * wpg[(4 * ic + j) * 9 + k];
        }
        wsb[i] = f2bf(v);
        return;
    }
    if (bid < 128) {                      // w2 fragment rows (PERMUTED out-ch)
        int i = (bid - 64) * 256 + tid;
        int f = i >> 7, col = i & 127;
        wsb[16384 + i] = f2bf(w2g[permch(f) * 128 + col]);
        return;
    }
    if (bid == 128) {                     // w3 [12][128] -> [16][128] pad
        for (int j = tid; j < 2048; j += 256)
            wsb[32768 + j] = (j < 1536) ? f2bf(w3g[j]) : (short)0;
        return;
    }
    if (bid == 129) {                     // b1' = b1 + w1.bp ; b2 copy (identity)
        if (tid < 128) {
            float s = b1g[tid];
            #pragma unroll 4
            for (int c = 0; c < 48; ++c) s += w1g[tid * 48 + c] * bpg[c];
            wsf[WSF_B1 + tid] = s;
        } else {
            wsf[WSF_B2 + (tid - 128)] = b2g[tid - 128];
        }
        return;
    }
    int b = bid - 130;                    // time embedding, one block per batch
    int lane = threadIdx.x;
    if (lane >= 64) return;
    float tv = (float)t[b];
    float s0 = 0.f, s1 = 0.f, s2 = 0.f;
    const float LOG1E4 = 9.210340371976184f;
    #pragma unroll
    for (int ii = 0; ii < 2; ++ii) {
        int i = lane + ii * 64;
        float invf = __expf(-LOG1E4 * (float)i * (1.0f / 128.0f));
        float ang = tv * invf;
        float sn = sinf(ang), cs = cosf(ang);
        float ss = sn / (1.0f + __expf(-sn));
        float sc = cs / (1.0f + __expf(-cs));
        s0 += ss * wt[0 * 256 + i] + sc * wt[0 * 256 + i + 128];
        s1 += ss * wt[1 * 256 + i] + sc * wt[1 * 256 + i + 128];
        s2 += ss * wt[2 * 256 + i] + sc * wt[2 * 256 + i + 128];
    }
    #pragma unroll
    for (int off = 32; off; off >>= 1) {
        s0 += __shfl_down(s0, off);
        s1 += __shfl_down(s1, off);
        s2 += __shfl_down(s2, off);
    }
    if (lane == 0) {
        wsf[WSF_EMB + b * 3 + 0] = s0 + bt[0];
        wsf[WSF_EMB + b * 3 + 1] = s1 + bt[1];
        wsf[WSF_EMB + b * 3 + 2] = s2 + bt[2];
    }
}

// ---------------- main fused kernel ----------------
// MFMA 16x16x32 (m89): A lane(i=lane&15,q) holds A[i][q*8+j]; B symmetric:
// lane holds B[q*8+j][i]. D: col(N)=lane&15, row(M)=q*4+r.
// With permch'd A-fragments, lane (m,q)'s c0(j=0)+c1(j=1) = chs base+8q+0..7
// (contiguous) for px=m -> one uint4 LDS write; positions stay ch-indexed.
__global__ __launch_bounds__(256, 3) void canet_main(
    const float* __restrict__ xg,   // (16,3,256,256)
    const float* __restrict__ hg,   // (16,9,256,256)
    const short* __restrict__ wsb,
    const float* __restrict__ wsf,
    float* __restrict__ outg)
{
    __shared__ __align__(16) short buf0[64 * ACT_S];   // ping-pong A
    __shared__ __align__(16) short buf1[64 * ACT_S];   // ping-pong B
    __shared__ __align__(16) short w3_s[16 * 128];     // [oc pad16][k], col XOR-swizzled
    __shared__ __align__(16) float bias_s[256];        // b1' @0, b2 @128

    const int tid = threadIdx.x;
    const int b = blockIdx.x >> 8;
    const int y = blockIdx.x & 255;

    bias_s[tid] = wsf[WSF_B1 + tid];                   // b1'[0:128], b2[128:256]
    for (int i = tid; i < 2048; i += 256) {            // w3 [16][128] swizzled
        int row = i >> 7, col = i & 127;
        w3_s[(row << 7) + (col ^ ((row & 7) << 3))] = wsb[32768 + i];
    }

    const int wv = tid >> 6;
    const int lane = tid & 63;
    const int m = lane & 15;
    const int q = lane >> 4;

    // ---- persistent weight fragments (Wf, w2; 64 regs; rows pre-permuted) ----
    bf16x8 w1f[2][4], w2f[2][4];
    #pragma unroll
    for (int j = 0; j < 2; ++j) {
        int n = wv * 32 + j * 16 + m;
        #pragma unroll
        for (int ks = 0; ks < 4; ++ks) {
            w1f[j][ks] = *(const bf16x8*)(wsb + n * 128 + ks * 32 + q * 8);
            w2f[j][ks] = *(const bf16x8*)(wsb + 16384 + n * 128 + ks * 32 + q * 8);
        }
    }
    const float embv = (m < 3) ? wsf[WSF_EMB + b * 3 + m] : 0.0f;

    // conv source pointers (lane's 3 input channels: ic = 3q + i3)
    const float* src3[3];
    #pragma unroll
    for (int i3 = 0; i3 < 3; ++i3) {
        int ic = 3 * q + i3;
        src3[i3] = (ic < 3) ? (xg + (((size_t)b * 3 + ic) << 16))
                            : (hg + (((size_t)b * 9 + (ic - 3)) << 16));
    }
    // clamped y-row offsets + validity (uniform per block)
    int yoff[3]; bool yokk[3];
    #pragma unroll
    for (int ky = 0; ky < 3; ++ky) {
        int yy = y + ky - 1;
        yokk[ky] = (yy >= 0) && (yy < 256);
        yoff[ky] = (yokk[ky] ? yy : y) * 256;
    }

    // raw (unmasked, addr-clamped) tap loads for pixel pxl into tp[27]
    auto load_taps = [&](float (&tp)[27], int pxl) {
        const int xm1 = pxl - (pxl > 0);
        const int xp1 = pxl + (pxl < 255);
        #pragma unroll
        for (int i3 = 0; i3 < 3; ++i3) {
            #pragma unroll
            for (int ky = 0; ky < 3; ++ky) {
                const float* rp = src3[i3] + yoff[ky];
                tp[i3 * 9 + ky * 3 + 0] = rp[xm1];
                tp[i3 * 9 + ky * 3 + 1] = rp[pxl];
                tp[i3 * 9 + ky * 3 + 2] = rp[xp1];
            }
        }
    };

    // mask prefetched taps -> bf16 -> 4 x uint4 -> dst[row][32q..]
    auto stage_taps = [&](short* dst, const float (&tp)[27], int pxl) {
        const bool okl = (pxl > 0), okr = (pxl < 255);
        short* prow = dst + (wv * 16 + m) * ACT_S + 32 * q;
        unsigned rr[16];
        rr[15] = 0u;                                  // shorts 30,31 pad
        #pragma unroll
        for (int i3 = 0; i3 < 3; ++i3) {
            float tm[9];
            #pragma unroll
            for (int ky = 0; ky < 3; ++ky) {
                int o = i3 * 9 + ky * 3;
                tm[ky * 3 + 0] = (yokk[ky] && okl) ? tp[o + 0] : 0.0f;
                tm[ky * 3 + 1] = yokk[ky] ? tp[o + 1] : 0.0f;
                tm[ky * 3 + 2] = (yokk[ky] && okr) ? tp[o + 2] : 0.0f;
            }
            rr[5 * i3 + 0] = pk2bf(tm[0], tm[1]);
            rr[5 * i3 + 1] = pk2bf(tm[2], tm[3]);
            rr[5 * i3 + 2] = pk2bf(tm[4], tm[5]);
            rr[5 * i3 + 3] = pk2bf(tm[6], tm[7]);
            rr[5 * i3 + 4] = pk2bf(tm[8], 0.0f);      // k=9 pad
        }
        #pragma unroll
        for (int w = 0; w < 4; ++w) {
            uint4 v; v.x = rr[4*w]; v.y = rr[4*w+1]; v.z = rr[4*w+2]; v.w = rr[4*w+3];
            *(uint4*)(prow + 8 * w) = v;
        }
    };

    const int w3sw = (m & 7) << 3;

    float tp[27];
    load_taps(tp, wv * 16 + m);          // taps_0
    stage_taps(buf0, tp, wv * 16 + m);   // im2col_0 -> buf0 (pre-barrier ok)

    __syncthreads();   // weights/bias/w3 + im2col_0 ready

    short* cur = buf0;   // holds im2col_t, later h2_t
    short* alt = buf1;   // holds h1_t; staging_{t+1} target

    for (int it = 0; it < 4; ++it) {
        const int x0 = it * 64;
        const int px = x0 + wv * 16 + m;

        // issue taps_{t+1} now; consumed in this iter's G3-phase staging
        if (it < 3) load_taps(tp, px + 64);

        // ---- GEMM1 (swapped, permuted): read cur(im2col), write alt(h1) ----
        #pragma unroll
        for (int nt = 0; nt < 4; ++nt) {
            f32x4 c0 = *(const f32x4*)(bias_s + wv * 32 + 8 * q);
            f32x4 c1 = *(const f32x4*)(bias_s + wv * 32 + 8 * q + 4);
            #pragma unroll
            for (int ks = 0; ks < 4; ++ks) {
                bf16x8 p = *(const bf16x8*)(cur + (nt * 16 + m) * ACT_S + ks * 32 + q * 8);
                c0 = __builtin_amdgcn_mfma_f32_16x16x32_bf16(w1f[0][ks], p, c0, 0, 0, 0);
                c1 = __builtin_amdgcn_mfma_f32_16x16x32_bf16(w1f[1][ks], p, c1, 0, 0, 0);
            }
            short* drow = alt + (nt * 16 + m) * ACT_S + wv * 32 + 8 * q;
            uint4 pk4;
            pk4.x = pk2bf(fmaxf(c0[0], 0.f), fmaxf(c0[1], 0.f));
            pk4.y = pk2bf(fmaxf(c0[2], 0.f), fmaxf(c0[3], 0.f));
            pk4.z = pk2bf(fmaxf(c1[0], 0.f), fmaxf(c1[1], 0.f));
            pk4.w = pk2bf(fmaxf(c1[2], 0.f), fmaxf(c1[3], 0.f));
            *(uint4*)drow = pk4;
        }
        __syncthreads();   // Bb: h1 ready in alt; im2col (cur) fully read

        // ---- GEMM2 (swapped, permuted): read alt(h1), write cur(h2) ----
        #pragma unroll
        for (int nt = 0; nt < 4; ++nt) {
            f32x4 c0 = *(const f32x4*)(bias_s + 128 + wv * 32 + 8 * q);
            f32x4 c1 = *(const f32x4*)(bias_s + 128 + wv * 32 + 8 * q + 4);
            #pragma unroll
            for (int ks = 0; ks < 4; ++ks) {
                bf16x8 a = *(const bf16x8*)(alt + (nt * 16 + m) * ACT_S + ks * 32 + q * 8);
                c0 = __builtin_amdgcn_mfma_f32_16x16x32_bf16(w2f[0][ks], a, c0, 0, 0, 0);
                c1 = __builtin_amdgcn_mfma_f32_16x16x32_bf16(w2f[1][ks], a, c1, 0, 0, 0);
            }
            short* drow = cur + (nt * 16 + m) * ACT_S + wv * 32 + 8 * q;
            uint4 pk4;
            pk4.x = pk2bf(fmaxf(c0[0], 0.f), fmaxf(c0[1], 0.f));
            pk4.y = pk2bf(fmaxf(c0[2], 0.f), fmaxf(c0[3], 0.f));
            pk4.z = pk2bf(fmaxf(c1[0], 0.f), fmaxf(c1[1], 0.f));
            pk4.w = pk2bf(fmaxf(c1[2], 0.f), fmaxf(c1[3], 0.f));
            *(uint4*)drow = pk4;
        }
        __syncthreads();   // Bc: h2 ready in cur; h1 (alt) fully read

        // ---- GEMM3 (read cur) PARALLEL staging_{t+1} (write alt) ----
        {
            f32x4 acc = {0.f, 0.f, 0.f, 0.f};
            #pragma unroll
            for (int ks = 0; ks < 4; ++ks) {
                bf16x8 a = *(const bf16x8*)(cur + (wv * 16 + m) * ACT_S + ks * 32 + q * 8);
                bf16x8 w3k = *(const bf16x8*)(w3_s + (m << 7) + ((ks * 32 + q * 8) ^ w3sw));
                acc = __builtin_amdgcn_mfma_f32_16x16x32_bf16(a, w3k, acc, 0, 0, 0);
            }
            if (it < 3) stage_taps(alt, tp, px + 64);   // im2col_{t+1} -> alt
            if (m < 12) {
                int xx0 = x0 + wv * 16 + q * 4;
                size_t idx;
                if (m < 3) {
                    idx = (size_t)NOISE_BASE + (((size_t)b * 3 + m) << 16) + (size_t)y * 256 + xx0;
                } else {
                    idx = (((size_t)b * 9 + (m - 3)) << 16) + (size_t)y * 256 + xx0;
                }
                f32x4 vst = {acc[0] + embv, acc[1] + embv, acc[2] + embv, acc[3] + embv};
                *(f32x4*)(outg + idx) = vst;
            }
        }
        if (it < 3) {
            __syncthreads();   // Ba: G3 done reading cur; im2col_{t+1} ready
            short* t_ = cur; cur = alt; alt = t_;
        }
    }
}

extern "C" void kernel_launch(void* const* d_in, const int* in_sizes, int n_in,
                              void* d_out, int out_size, void* d_ws, size_t ws_size,
                              hipStream_t stream) {
    const float* xg  = (const float*)d_in[0];
    const float* hg  = (const float*)d_in[1];
    const int*   tg  = (const int*)  d_in[2];
    const float* wpg = (const float*)d_in[3];
    const float* bpg = (const float*)d_in[4];
    const float* w1g = (const float*)d_in[5];
    const float* b1g = (const float*)d_in[6];
    const float* w2g = (const float*)d_in[7];
    const float* b2g = (const float*)d_in[8];
    const float* w3g = (const float*)d_in[9];
    const float* wtg = (const float*)d_in[10];
    const float* btg = (const float*)d_in[11];
    float* outg = (float*)d_out;
    short* wsb  = (short*)d_ws;
    float* wsf  = (float*)d_ws + WSF_OFF;

    prep_emb_kernel<<<146, 256, 0, stream>>>(wpg, bpg, w1g, b1g, w2g, b2g, w3g,
                                             tg, wtg, btg, wsb, wsf);
    canet_main<<<4096, 256, 0, stream>>>(xg, hg, wsb, wsf, outg);
}

// Round 14
// 200.477 us; speedup vs baseline: 1.0620x; 1.0620x over previous
//
#include <hip/hip_runtime.h>

// CANet fused kernel, round 19.
// Post-mortem r18: ping-pong/barrier-count REGRESSED (116->124.4): merging
// staging into G3 serialized the same work within each wave; phase count is
// not the cost. REVERTED to r17 structure (116us best).
// Sharper theory: hipcc emits s_waitcnt vmcnt(0) lgkmcnt(0) before EVERY
// s_barrier (guide: barrier-drain stall). 16 drains/block force the 27
// HBM-cold tap loads (~900cyc) to complete within ONE phase (~700cyc) -> a
// guaranteed stall per iter, plus pointless outg-store drains at B4.
// r19 = r17 + ONE change: in-loop barriers become lgkmcnt(0)-only
// (asm s_waitcnt lgkmcnt(0); s_barrier -- HK/m201 pattern). LDS ordering
// preserved (all ds ops drain); vmcnt deps (taps->staging) are tracked by the
// compiler at the use site; outg stores never need a drain. Tap-load cover
// becomes G1+G2+G3 ~2.5K cyc >> 900.
// Canaries: absmax must stay 0.0078125 (race); FETCH/WRITE/VGPR flat (spill).
// If dur flat: drains weren't the stall -> structure plateau, consider stop.

#define ACT_S 136     // 272 B rows (16B-aligned) for bufA/h1S [px][ch]
#define NOISE_BASE 9437184   // 16*9*65536

// d_ws shorts: Wf[128][128]@0, w2[128][128]@16384, w3[16][128]@32768 (2048)
// floats @ WSF_OFF: b1'[128]@0, b2[128]@128, emb[48]@256
#define WSF_OFF 17408
#define WSF_B1 0
#define WSF_B2 128
#define WSF_EMB 256

// lgkm-only barrier: LDS ordering without the vmcnt(0) drain
#define SBAR() do { asm volatile("s_waitcnt lgkmcnt(0)" ::: "memory"); \
                    __builtin_amdgcn_s_barrier(); } while (0)

typedef short bf16x8 __attribute__((ext_vector_type(8)));
typedef float f32x4 __attribute__((ext_vector_type(4)));

__device__ __forceinline__ short f2bf(float f) {
    union { float f; unsigned u; } cv; cv.f = f;
    unsigned r = cv.u + 0x7FFFu + ((cv.u >> 16) & 1u);
    return (short)(r >> 16);
}
// pack two fp32 -> dword of two bf16 (round-half-up): lo16=bf(f0), hi16=bf(f1)
__device__ __forceinline__ unsigned pk2bf(float f0, float f1) {
    union { float f; unsigned u; } a, b; a.f = f0; b.f = f1;
    return __builtin_amdgcn_perm(b.u + 0x8000u, a.u + 0x8000u, 0x07060302u);
}

// fragment-row -> actual channel permutation (within each 32-ch wave block):
// f = base(32) + 16*j + i  ->  o = base + 8*(i>>2) + 4*j + (i&3)
__device__ __forceinline__ int permch(int f) {
    return (f & ~31) + 8 * ((f & 15) >> 2) + 4 * ((f >> 4) & 1) + (f & 3);
}

// ---------------- weight prep (fused Wf/b1') + time embedding ----------------
__global__ void prep_emb_kernel(const float* __restrict__ wpg, const float* __restrict__ bpg,
                                const float* __restrict__ w1g, const float* __restrict__ b1g,
                                const float* __restrict__ w2g, const float* __restrict__ b2g,
                                const float* __restrict__ w3g,
                                const int* __restrict__ t,
                                const float* __restrict__ wt, const float* __restrict__ bt,
                                short* __restrict__ wsb, float* __restrict__ wsf)
{
    const int bid = blockIdx.x, tid = threadIdx.x;
    if (bid < 64) {                       // Wf fragment rows (PERMUTED out-ch)
        int i = bid * 256 + tid;
        int f = i >> 7, kk = i & 127;
        int o = permch(f);
        int qq = kk >> 5, r = kk & 31;
        float v = 0.f;
        if (r < 30 && (r % 10) < 9) {
            int c3 = r / 10, k = r % 10;
            int ic = 3 * qq + c3;
            #pragma unroll
            for (int j = 0; j < 4; ++j)
                v += w1g[o * 48 + 4 * ic + j] * wpg[(4 * ic + j) * 9 + k];
        }
        wsb[i] = f2bf(v);
        return;
    }
    if (bid < 128) {                      // w2 fragment rows (PERMUTED out-ch)
        int i = (bid - 64) * 256 + tid;
        int f = i >> 7, col = i & 127;
        wsb[16384 + i] = f2bf(w2g[permch(f) * 128 + col]);
        return;
    }
    if (bid == 128) {                     // w3 [12][128] -> [16][128] pad
        for (int j = tid; j < 2048; j += 256)
            wsb[32768 + j] = (j < 1536) ? f2bf(w3g[j]) : (short)0;
        return;
    }
    if (bid == 129) {                     // b1' = b1 + w1.bp ; b2 copy (identity)
        if (tid < 128) {
            float s = b1g[tid];
            #pragma unroll 4
            for (int c = 0; c < 48; ++c) s += w1g[tid * 48 + c] * bpg[c];
            wsf[WSF_B1 + tid] = s;
        } else {
            wsf[WSF_B2 + (tid - 128)] = b2g[tid - 128];
        }
        return;
    }
    int b = bid - 130;                    // time embedding, one block per batch
    int lane = threadIdx.x;
    if (lane >= 64) return;
    float tv = (float)t[b];
    float s0 = 0.f, s1 = 0.f, s2 = 0.f;
    const float LOG1E4 = 9.210340371976184f;
    #pragma unroll
    for (int ii = 0; ii < 2; ++ii) {
        int i = lane + ii * 64;
        float invf = __expf(-LOG1E4 * (float)i * (1.0f / 128.0f));
        float ang = tv * invf;
        float sn = sinf(ang), cs = cosf(ang);
        float ss = sn / (1.0f + __expf(-sn));
        float sc = cs / (1.0f + __expf(-cs));
        s0 += ss * wt[0 * 256 + i] + sc * wt[0 * 256 + i + 128];
        s1 += ss * wt[1 * 256 + i] + sc * wt[1 * 256 + i + 128];
        s2 += ss * wt[2 * 256 + i] + sc * wt[2 * 256 + i + 128];
    }
    #pragma unroll
    for (int off = 32; off; off >>= 1) {
        s0 += __shfl_down(s0, off);
        s1 += __shfl_down(s1, off);
        s2 += __shfl_down(s2, off);
    }
    if (lane == 0) {
        wsf[WSF_EMB + b * 3 + 0] = s0 + bt[0];
        wsf[WSF_EMB + b * 3 + 1] = s1 + bt[1];
        wsf[WSF_EMB + b * 3 + 2] = s2 + bt[2];
    }
}

// ---------------- main fused kernel ----------------
// MFMA 16x16x32 (m89): A lane(i=lane&15,q) holds A[i][q*8+j]; B symmetric:
// lane holds B[q*8+j][i]. D: col(N)=lane&15, row(M)=q*4+r.
// With permch'd A-fragments, lane (m,q)'s c0(j=0)+c1(j=1) = chs base+8q+0..7
// (contiguous) for px=m -> one uint4 LDS write; positions stay ch-indexed.
__global__ __launch_bounds__(256, 3) void canet_main(
    const float* __restrict__ xg,   // (16,3,256,256)
    const float* __restrict__ hg,   // (16,9,256,256)
    const short* __restrict__ wsb,
    const float* __restrict__ wsf,
    float* __restrict__ outg)
{
    __shared__ __align__(16) short bufA[64 * ACT_S];   // im2col / h2
    __shared__ __align__(16) short h1S[64 * ACT_S];
    __shared__ __align__(16) short w3_s[16 * 128];     // [oc pad16][k], col XOR-swizzled
    __shared__ __align__(16) float bias_s[256];        // b1' @0, b2 @128

    const int tid = threadIdx.x;
    const int b = blockIdx.x >> 8;
    const int y = blockIdx.x & 255;

    bias_s[tid] = wsf[WSF_B1 + tid];                   // b1'[0:128], b2[128:256]
    for (int i = tid; i < 2048; i += 256) {            // w3 [16][128] swizzled
        int row = i >> 7, col = i & 127;
        w3_s[(row << 7) + (col ^ ((row & 7) << 3))] = wsb[32768 + i];
    }

    const int wv = tid >> 6;
    const int lane = tid & 63;
    const int m = lane & 15;
    const int q = lane >> 4;

    // ---- persistent weight fragments (Wf, w2; 64 regs; rows pre-permuted) ----
    bf16x8 w1f[2][4], w2f[2][4];
    #pragma unroll
    for (int j = 0; j < 2; ++j) {
        int n = wv * 32 + j * 16 + m;
        #pragma unroll
        for (int ks = 0; ks < 4; ++ks) {
            w1f[j][ks] = *(const bf16x8*)(wsb + n * 128 + ks * 32 + q * 8);
            w2f[j][ks] = *(const bf16x8*)(wsb + 16384 + n * 128 + ks * 32 + q * 8);
        }
    }
    const float embv = (m < 3) ? wsf[WSF_EMB + b * 3 + m] : 0.0f;

    // conv source pointers (lane's 3 input channels: ic = 3q + i3)
    const float* src3[3];
    #pragma unroll
    for (int i3 = 0; i3 < 3; ++i3) {
        int ic = 3 * q + i3;
        src3[i3] = (ic < 3) ? (xg + (((size_t)b * 3 + ic) << 16))
                            : (hg + (((size_t)b * 9 + (ic - 3)) << 16));
    }
    // clamped y-row offsets + validity (uniform per block)
    int yoff[3]; bool yokk[3];
    #pragma unroll
    for (int ky = 0; ky < 3; ++ky) {
        int yy = y + ky - 1;
        yokk[ky] = (yy >= 0) && (yy < 256);
        yoff[ky] = (yokk[ky] ? yy : y) * 256;
    }

    // raw (unmasked, addr-clamped) tap loads for pixel pxl into tp[27]
    auto load_taps = [&](float (&tp)[27], int pxl) {
        const int xm1 = pxl - (pxl > 0);
        const int xp1 = pxl + (pxl < 255);
        #pragma unroll
        for (int i3 = 0; i3 < 3; ++i3) {
            #pragma unroll
            for (int ky = 0; ky < 3; ++ky) {
                const float* rp = src3[i3] + yoff[ky];
                tp[i3 * 9 + ky * 3 + 0] = rp[xm1];
                tp[i3 * 9 + ky * 3 + 1] = rp[pxl];
                tp[i3 * 9 + ky * 3 + 2] = rp[xp1];
            }
        }
    };

    const int w3sw = (m & 7) << 3;

    float tp[27];
    load_taps(tp, wv * 16 + m);     // it=0 prefetch (global only, pre-barrier ok)

    __syncthreads();   // full drain once: staged LDS ready

    for (int it = 0; it < 4; ++it) {
        const int x0 = it * 64;
        const int px = x0 + wv * 16 + m;

        // ---- im2col staging: mask prefetched taps -> bf16 -> 4 x uint4 ----
        {
            const bool okl = (px > 0), okr = (px < 255);
            short* prow = bufA + (wv * 16 + m) * ACT_S + 32 * q;
            unsigned rr[16];
            rr[15] = 0u;                                  // shorts 30,31 pad
            #pragma unroll
            for (int i3 = 0; i3 < 3; ++i3) {
                float tm[9];
                #pragma unroll
                for (int ky = 0; ky < 3; ++ky) {
                    int o = i3 * 9 + ky * 3;
                    tm[ky * 3 + 0] = (yokk[ky] && okl) ? tp[o + 0] : 0.0f;
                    tm[ky * 3 + 1] = yokk[ky] ? tp[o + 1] : 0.0f;
                    tm[ky * 3 + 2] = (yokk[ky] && okr) ? tp[o + 2] : 0.0f;
                }
                rr[5 * i3 + 0] = pk2bf(tm[0], tm[1]);
                rr[5 * i3 + 1] = pk2bf(tm[2], tm[3]);
                rr[5 * i3 + 2] = pk2bf(tm[4], tm[5]);
                rr[5 * i3 + 3] = pk2bf(tm[6], tm[7]);
                rr[5 * i3 + 4] = pk2bf(tm[8], 0.0f);      // k=9 pad
            }
            #pragma unroll
            for (int w = 0; w < 4; ++w) {
                uint4 v; v.x = rr[4*w]; v.y = rr[4*w+1]; v.z = rr[4*w+2]; v.w = rr[4*w+3];
                *(uint4*)(prow + 8 * w) = v;
            }
        }
        SBAR();   // B1: im2col ready (lgkm only)

        // prefetch it+1's taps; with non-draining barriers the loads stay in
        // flight across B2/B3/B4 -> cover = G1+G2+G3 ~2.5K cyc >> 900
        if (it < 3) load_taps(tp, px + 64);

        // ---- GEMM1 (swapped, permuted): write h1S[px][ch] as one uint4 ----
        #pragma unroll
        for (int nt = 0; nt < 4; ++nt) {
            f32x4 c0 = *(const f32x4*)(bias_s + wv * 32 + 8 * q);
            f32x4 c1 = *(const f32x4*)(bias_s + wv * 32 + 8 * q + 4);
            #pragma unroll
            for (int ks = 0; ks < 4; ++ks) {
                bf16x8 p = *(const bf16x8*)(bufA + (nt * 16 + m) * ACT_S + ks * 32 + q * 8);
                c0 = __builtin_amdgcn_mfma_f32_16x16x32_bf16(w1f[0][ks], p, c0, 0, 0, 0);
                c1 = __builtin_amdgcn_mfma_f32_16x16x32_bf16(w1f[1][ks], p, c1, 0, 0, 0);
            }
            short* drow = h1S + (nt * 16 + m) * ACT_S + wv * 32 + 8 * q;
            uint4 pk4;
            pk4.x = pk2bf(fmaxf(c0[0], 0.f), fmaxf(c0[1], 0.f));
            pk4.y = pk2bf(fmaxf(c0[2], 0.f), fmaxf(c0[3], 0.f));
            pk4.z = pk2bf(fmaxf(c1[0], 0.f), fmaxf(c1[1], 0.f));
            pk4.w = pk2bf(fmaxf(c1[2], 0.f), fmaxf(c1[3], 0.f));
            *(uint4*)drow = pk4;
        }
        SBAR();   // B2: h1 ready; im2col fully read

        // ---- GEMM2 (swapped, permuted): write h2 -> bufA as one uint4 ----
        #pragma unroll
        for (int nt = 0; nt < 4; ++nt) {
            f32x4 c0 = *(const f32x4*)(bias_s + 128 + wv * 32 + 8 * q);
            f32x4 c1 = *(const f32x4*)(bias_s + 128 + wv * 32 + 8 * q + 4);
            #pragma unroll
            for (int ks = 0; ks < 4; ++ks) {
                bf16x8 a = *(const bf16x8*)(h1S + (nt * 16 + m) * ACT_S + ks * 32 + q * 8);
                c0 = __builtin_amdgcn_mfma_f32_16x16x32_bf16(w2f[0][ks], a, c0, 0, 0, 0);
                c1 = __builtin_amdgcn_mfma_f32_16x16x32_bf16(w2f[1][ks], a, c1, 0, 0, 0);
            }
            short* drow = bufA + (nt * 16 + m) * ACT_S + wv * 32 + 8 * q;
            uint4 pk4;
            pk4.x = pk2bf(fmaxf(c0[0], 0.f), fmaxf(c0[1], 0.f));
            pk4.y = pk2bf(fmaxf(c0[2], 0.f), fmaxf(c0[3], 0.f));
            pk4.z = pk2bf(fmaxf(c1[0], 0.f), fmaxf(c1[1], 0.f));
            pk4.w = pk2bf(fmaxf(c1[2], 0.f), fmaxf(c1[3], 0.f));
            *(uint4*)drow = pk4;
        }
        SBAR();   // B3: h2 ready

        // ---- GEMM3: out = h2 . w3^T ; D col=oc, row=px; float4 store ----
        {
            f32x4 acc = {0.f, 0.f, 0.f, 0.f};
            #pragma unroll
            for (int ks = 0; ks < 4; ++ks) {
                bf16x8 a = *(const bf16x8*)(bufA + (wv * 16 + m) * ACT_S + ks * 32 + q * 8);
                bf16x8 w3k = *(const bf16x8*)(w3_s + (m << 7) + ((ks * 32 + q * 8) ^ w3sw));
                acc = __builtin_amdgcn_mfma_f32_16x16x32_bf16(a, w3k, acc, 0, 0, 0);
            }
            if (m < 12) {
                int xx0 = x0 + wv * 16 + q * 4;
                size_t idx;
                if (m < 3) {
                    idx = (size_t)NOISE_BASE + (((size_t)b * 3 + m) << 16) + (size_t)y * 256 + xx0;
                } else {
                    idx = (((size_t)b * 9 + (m - 3)) << 16) + (size_t)y * 256 + xx0;
                }
                f32x4 vst = {acc[0] + embv, acc[1] + embv, acc[2] + embv, acc[3] + embv};
                *(f32x4*)(outg + idx) = vst;
            }
        }
        SBAR();   // B4: bufA fully read; next staging may overwrite
    }
}

extern "C" void kernel_launch(void* const* d_in, const int* in_sizes, int n_in,
                              void* d_out, int out_size, void* d_ws, size_t ws_size,
                              hipStream_t stream) {
    const float* xg  = (const float*)d_in[0];
    const float* hg  = (const float*)d_in[1];
    const int*   tg  = (const int*)  d_in[2];
    const float* wpg = (const float*)d_in[3];
    const float* bpg = (const float*)d_in[4];
    const float* w1g = (const float*)d_in[5];
    const float* b1g = (const float*)d_in[6];
    const float* w2g = (const float*)d_in[7];
    const float* b2g = (const float*)d_in[8];
    const float* w3g = (const float*)d_in[9];
    const float* wtg = (const float*)d_in[10];
    const float* btg = (const float*)d_in[11];
    float* outg = (float*)d_out;
    short* wsb  = (short*)d_ws;
    float* wsf  = (float*)d_ws + WSF_OFF;

    prep_emb_kernel<<<146, 256, 0, stream>>>(wpg, bpg, w1g, b1g, w2g, b2g, w3g,
                                             tg, wtg, btg, wsb, wsf);
    canet_main<<<4096, 256, 0, stream>>>(xg, hg, wsb, wsf, outg);
}